// Round 16
// baseline (175.090 us; speedup 1.0000x reference)
//
#include <hip/hip_runtime.h>
#include <stdint.h>

// B=4 N=32 L=S=256 H=8 E=D=64
// R15 = R13 (persistent 256-block grid, 4 bnh/block; per-tile double-buffered
// 4KB K/V slices; lgkm-only barriers; swapped-MFMA body; depth-1 prior
// prefetch) with ONE change: score stores are PLAIN (not nontemporal).
// Theory: nt stores evict-first -> 64B partial-line writebacks (each dwordx4
// covers only half of each 128B line; the matching half arrives in a later
// instruction) -> HBM read-modify-write inflates effective write cost ~2x.
// Plain stores let L2 merge both 64B halves, then write back full lines.

typedef __attribute__((ext_vector_type(8))) short bfrag;   // 8 bf16 (4 VGPRs)
typedef __attribute__((ext_vector_type(4))) float f32x4;
typedef __attribute__((ext_vector_type(2))) float f32x2;
typedef __attribute__((ext_vector_type(4))) int i32x4;

__device__ __forceinline__ uint32_t f2bf(float f) {
  uint32_t u = __builtin_bit_cast(uint32_t, f);
  return (u + 0x7FFFu + ((u >> 16) & 1u)) >> 16;   // RNE f32->bf16 (finite data)
}
__device__ __forceinline__ uint32_t pk(float a, float b) {
  return f2bf(a) | (f2bf(b) << 16);
}

#define MFMA(a, b, c) __builtin_amdgcn_mfma_f32_16x16x32_bf16((a), (b), (c), 0, 0, 0)

__global__ __launch_bounds__(1024, 2) void attn_kernel(
    const float* __restrict__ Qg, const float* __restrict__ Kg,
    const float* __restrict__ Vg, const float* __restrict__ Pg,
    float* __restrict__ Sc, float* __restrict__ Ov)
{
  // K slice: [32 s][64 e] bf16, 128B rows, byte ^= (s&7)<<4   (4096 B x2)
  // V slice: [64 d][32 s] bf16, 64B rows,  byte ^= (d&3)<<4   (4096 B x2)
  __shared__ char Kb[2][4096];
  __shared__ char Vb[2][4096];

  const int t = threadIdx.x;
  const int lane = t & 63;
  const int wave = t >> 6;    // 0..15
  const int ql = lane & 15;   // q within 16-tile (MFMA col)
  const int g  = lane >> 4;   // 4-group (MFMA row group / k-slice)
  // magic-square q-tile permutation (per-SIMD PV balance)
  const int qt = (int)((0x783C96D25A1EB4F0ull >> (wave * 4)) & 15);
  const int q = qt * 16 + ql;
  const int pvmax = qt >> 1;        // causal: PV only for st <= pvmax
  const int swzk = (ql & 7) << 4;   // K slice read swizzle (lane-constant)
  const int swzv = (ql & 3) << 4;   // V slice read swizzle
  const float temp = 0.125f;        // 1/sqrt(64)

  // ---- staging roles (thread-constant) ----
  const int kr_ = t >> 5;          // K slice row 0..31
  const int kc_ = t & 31;          // K f32-pair col (floats 2*kc_)
  const int vd_ = t & 63;          // V: d
  const int vw_ = t >> 6;          // V: s-pair index 0..15
  const int kwoff = (kr_ * 128 + kc_ * 4) ^ ((kr_ & 7) << 4);
  const int vwoff = (vd_ * 64 + vw_ * 4) ^ ((vd_ & 3) << 4);

#pragma unroll 1
  for (int bi = 0; bi < 4; ++bi) {
    const int bnh = (bi << 8) + blockIdx.x;
    const int bn = bnh >> 3, h = bnh & 7;

    const float* kgp = Kg + (size_t)bn * 131072 + h * 64 + (size_t)kr_ * 512 + 2 * kc_;
    const float* vgp = Vg + (size_t)bn * 131072 + h * 64 + (size_t)(2 * vw_) * 512 + vd_;

    // ---- prologue: stage tile 0 into buf 0, then issue tile-1 loads ----
    f32x2 kreg = *(const f32x2*)kgp;
    float vreg0 = vgp[0], vreg1 = vgp[512];
    *(uint32_t*)(&Kb[0][0] + kwoff) = pk(kreg[0], kreg[1]);
    *(uint32_t*)(&Vb[0][0] + vwoff) = pk(vreg0, vreg1);
    kreg = *(const f32x2*)(kgp + 16384);
    vreg0 = vgp[16384];
    vreg1 = vgp[16384 + 512];

    // ---- Q fragments direct from global (B-operand of swapped QK) ----
    bfrag qf[2];
#pragma unroll
    for (int ks = 0; ks < 2; ++ks) {
      const float* qp = Qg + (size_t)bn * 131072 + (size_t)q * 512 + h * 64 + ks * 32 + g * 8;
      const f32x4 qa = *(const f32x4*)qp;
      const f32x4 qb = *(const f32x4*)(qp + 4);
      union { i32x4 i; bfrag b; } u;
      u.i = i32x4{(int)pk(qa.x, qa.y), (int)pk(qa.z, qa.w),
                  (int)pk(qb.x, qb.y), (int)pk(qb.z, qb.w)};
      qf[ks] = u.b;
    }

    f32x4 O[4];
#pragma unroll
    for (int ds = 0; ds < 4; ++ds) O[ds] = f32x4{0.f, 0.f, 0.f, 0.f};
    float m = -1e30f, lsum = 0.f;

    const size_t scb = (size_t)bnh << 16;
    const float* prp = Pg + scb + (size_t)q * 256 + 4 * g;   // + 16*ss + 32*st
    float* scp = Sc + scb + (size_t)q * 256 + 4 * g;

    // prior pipeline: loop-carried scalars, loaded for tile 0 here
    f32x4 pr0 = __builtin_nontemporal_load((const f32x4*)(prp));
    f32x4 pr1 = __builtin_nontemporal_load((const f32x4*)(prp + 16));

    asm volatile("s_waitcnt lgkmcnt(0)" ::: "memory");
    __builtin_amdgcn_s_barrier();

#pragma unroll 1
    for (int st = 0; st < 8; ++st) {
      const int s0 = st * 32;
      const int p = (st & 1) << 12;
      bfrag kf[2][2];
#pragma unroll
      for (int ss = 0; ss < 2; ++ss)
#pragma unroll
        for (int ks = 0; ks < 2; ++ks)
          kf[ss][ks] = *(const bfrag*)(&Kb[0][0] + p +
              (((16 * ss + ql) * 128 + ks * 64 + g * 16) ^ swzk));

      // QK^T swapped -> D[s16][q16]; regs are s-consecutive at fixed q
      f32x4 acc[2];
#pragma unroll
      for (int ss = 0; ss < 2; ++ss) {
        f32x4 a = f32x4{0.f, 0.f, 0.f, 0.f};
        a = MFMA(kf[ss][0], qf[0], a);
        a = MFMA(kf[ss][1], qf[1], a);
        const int sb = s0 + 16 * ss + 4 * g;
        // analytic causal mask: s<=q allowed, else -1e9 (matches input mask)
#pragma unroll
        for (int r = 0; r < 4; ++r)
          a[r] = (sb + r <= q) ? a[r] : a[r] - 1e9f;
        acc[ss] = a + (ss == 0 ? pr0 : pr1);   // scores = QK + mask + prior
      }

      // prior consumed -> issue next tile's loads NOW
      if (st < 7) {
        pr0 = __builtin_nontemporal_load((const f32x4*)(prp + (st + 1) * 32));
        pr1 = __builtin_nontemporal_load((const f32x4*)(prp + (st + 1) * 32 + 16));
      }

      // scores out -- PLAIN stores (let L2 merge the two 64B half-lines)
      *(f32x4*)(scp + s0) = acc[0];
      *(f32x4*)(scp + s0 + 16) = acc[1];

      if (st <= pvmax) {  // tiles fully in the causal-masked region skip softmax/PV
        float tm = fmaxf(fmaxf(fmaxf(acc[0][0], acc[0][1]), fmaxf(acc[0][2], acc[0][3])),
                         fmaxf(fmaxf(acc[1][0], acc[1][1]), fmaxf(acc[1][2], acc[1][3])));
        tm = fmaxf(tm, __shfl_xor(tm, 16));
        tm = fmaxf(tm, __shfl_xor(tm, 32));
        tm *= temp;
        const float mnew = fmaxf(m, tm);
        const float fct = __expf(m - mnew);
        m = mnew;
        float pv[8];
#pragma unroll
        for (int ss = 0; ss < 2; ++ss)
#pragma unroll
          for (int r = 0; r < 4; ++r)
            pv[ss * 4 + r] = __expf(fmaf(temp, acc[ss][r], -mnew));
        float ts = (pv[0] + pv[1]) + (pv[2] + pv[3]) + (pv[4] + pv[5]) + (pv[6] + pv[7]);
        ts += __shfl_xor(ts, 16);
        ts += __shfl_xor(ts, 32);
        lsum = lsum * fct + ts;
#pragma unroll
        for (int ds = 0; ds < 4; ++ds) O[ds] *= fct;

        // pack P to bf16 and redistribute in-register to the PV B-fragment
        // layout (lane (ql,g) needs s = s0+8g..8g+7). Held: w0 = s 4g..4g+3,
        // w1 = s 16+4g..+3. Sources: lanes g'={2g&3,(2g+1)&3}, pick by g<2.
        const int w0x = (int)pk(pv[0], pv[1]), w0y = (int)pk(pv[2], pv[3]);
        const int w1x = (int)pk(pv[4], pv[5]), w1y = (int)pk(pv[6], pv[7]);
        const int srcA = ((g & 1) << 5) + ql;       // lane of g' = (2g)&3
        const int a0 = __shfl(w0x, srcA),      a1 = __shfl(w1x, srcA);
        const int b0 = __shfl(w0y, srcA),      b1 = __shfl(w1y, srcA);
        const int c0 = __shfl(w0x, srcA + 16), c1 = __shfl(w1x, srcA + 16);
        const int d0 = __shfl(w0y, srcA + 16), d1 = __shfl(w1y, srcA + 16);
        union { i32x4 i; bfrag b; } pu;
        pu.i = i32x4{g < 2 ? a0 : a1, g < 2 ? b0 : b1,
                     g < 2 ? c0 : c1, g < 2 ? d0 : d1};

        // PV swapped: O^T[d][q] += V^T[d x s32] * P^T[s32 x q16]
        bfrag vf[4];
#pragma unroll
        for (int ds = 0; ds < 4; ++ds)
          vf[ds] = *(const bfrag*)(&Vb[0][0] + p +
              (((16 * ds + ql) * 64 + g * 16) ^ swzv));
#pragma unroll
        for (int ds = 0; ds < 4; ++ds) O[ds] = MFMA(vf[ds], pu.b, O[ds]);
      }

      // write staged K/V regs (tile st+1) into the opposite buffer, then
      // issue tile st+2 loads into the same (now free) regs
      if (st < 7) {
        const int p1 = ((st + 1) & 1) << 12;
        *(uint32_t*)(&Kb[0][0] + p1 + kwoff) = pk(kreg[0], kreg[1]);
        *(uint32_t*)(&Vb[0][0] + p1 + vwoff) = pk(vreg0, vreg1);
        if (st < 6) {
          kreg = *(const f32x2*)(kgp + (size_t)(st + 2) * 16384);
          vreg0 = vgp[(st + 2) * 16384];
          vreg1 = vgp[(st + 2) * 16384 + 512];
        }
      }
      asm volatile("s_waitcnt lgkmcnt(0)" ::: "memory");
      __builtin_amdgcn_s_barrier();
    }

    // epilogue: O /= l, store dwordx4 (d-consecutive regs)
    {
      const float inv = 1.f / lsum;
      float* op = Ov + (size_t)bn * 131072 + (size_t)q * 512 + h * 64 + 4 * g;
#pragma unroll
      for (int ds = 0; ds < 4; ++ds) {
        f32x4 o = O[ds] * inv;
        *(f32x4*)(op + 16 * ds) = o;
      }
    }
  }
}

extern "C" void kernel_launch(void* const* d_in, const int* in_sizes, int n_in,
                              void* d_out, int out_size, void* d_ws, size_t ws_size,
                              hipStream_t stream) {
  const float* Qg = (const float*)d_in[0];   // queries  [B,N,L,H,E]
  const float* Kg = (const float*)d_in[1];   // keys     [B,N,S,H,E]
  const float* Vg = (const float*)d_in[2];   // values   [B,N,S,H,D]
  const float* Pg = (const float*)d_in[4];   // attn_scores [B,N,H,L,S]
  float* Sc = (float*)d_out;                            // scores out
  float* Ov = Sc + (size_t)4 * 32 * 8 * 256 * 256;      // V out
  attn_kernel<<<dim3(256), dim3(1024), 0, stream>>>(Qg, Kg, Vg, Pg, Sc, Ov);
}

// Round 17
// 173.711 us; speedup vs baseline: 1.0079x; 1.0079x over previous
//
#include <hip/hip_runtime.h>
#include <stdint.h>

// B=4 N=32 L=S=256 H=8 E=D=64
// R16 = R13 (persistent 256-block grid, 4 bnh/block; per-tile double-buffered
// 4KB K/V slices; lgkm-only barriers; swapped-MFMA body; depth-1 prior
// prefetch; NT score stores -- R15 proved removing them regresses) with ONE
// change: prior loads are PLAIN (not nontemporal). Theory: FETCH (231MB) <
// prior size (268MB) shows cross-replay L3 retention of the prior stream;
// evict-first NT loads undermine that retention. Plain loads -> better L3
// survival -> lower FETCH.

typedef __attribute__((ext_vector_type(8))) short bfrag;   // 8 bf16 (4 VGPRs)
typedef __attribute__((ext_vector_type(4))) float f32x4;
typedef __attribute__((ext_vector_type(2))) float f32x2;
typedef __attribute__((ext_vector_type(4))) int i32x4;

__device__ __forceinline__ uint32_t f2bf(float f) {
  uint32_t u = __builtin_bit_cast(uint32_t, f);
  return (u + 0x7FFFu + ((u >> 16) & 1u)) >> 16;   // RNE f32->bf16 (finite data)
}
__device__ __forceinline__ uint32_t pk(float a, float b) {
  return f2bf(a) | (f2bf(b) << 16);
}

#define MFMA(a, b, c) __builtin_amdgcn_mfma_f32_16x16x32_bf16((a), (b), (c), 0, 0, 0)

__global__ __launch_bounds__(1024, 2) void attn_kernel(
    const float* __restrict__ Qg, const float* __restrict__ Kg,
    const float* __restrict__ Vg, const float* __restrict__ Pg,
    float* __restrict__ Sc, float* __restrict__ Ov)
{
  // K slice: [32 s][64 e] bf16, 128B rows, byte ^= (s&7)<<4   (4096 B x2)
  // V slice: [64 d][32 s] bf16, 64B rows,  byte ^= (d&3)<<4   (4096 B x2)
  __shared__ char Kb[2][4096];
  __shared__ char Vb[2][4096];

  const int t = threadIdx.x;
  const int lane = t & 63;
  const int wave = t >> 6;    // 0..15
  const int ql = lane & 15;   // q within 16-tile (MFMA col)
  const int g  = lane >> 4;   // 4-group (MFMA row group / k-slice)
  // magic-square q-tile permutation (per-SIMD PV balance)
  const int qt = (int)((0x783C96D25A1EB4F0ull >> (wave * 4)) & 15);
  const int q = qt * 16 + ql;
  const int pvmax = qt >> 1;        // causal: PV only for st <= pvmax
  const int swzk = (ql & 7) << 4;   // K slice read swizzle (lane-constant)
  const int swzv = (ql & 3) << 4;   // V slice read swizzle
  const float temp = 0.125f;        // 1/sqrt(64)

  // ---- staging roles (thread-constant) ----
  const int kr_ = t >> 5;          // K slice row 0..31
  const int kc_ = t & 31;          // K f32-pair col (floats 2*kc_)
  const int vd_ = t & 63;          // V: d
  const int vw_ = t >> 6;          // V: s-pair index 0..15
  const int kwoff = (kr_ * 128 + kc_ * 4) ^ ((kr_ & 7) << 4);
  const int vwoff = (vd_ * 64 + vw_ * 4) ^ ((vd_ & 3) << 4);

#pragma unroll 1
  for (int bi = 0; bi < 4; ++bi) {
    const int bnh = (bi << 8) + blockIdx.x;
    const int bn = bnh >> 3, h = bnh & 7;

    const float* kgp = Kg + (size_t)bn * 131072 + h * 64 + (size_t)kr_ * 512 + 2 * kc_;
    const float* vgp = Vg + (size_t)bn * 131072 + h * 64 + (size_t)(2 * vw_) * 512 + vd_;

    // ---- prologue: stage tile 0 into buf 0, then issue tile-1 loads ----
    f32x2 kreg = *(const f32x2*)kgp;
    float vreg0 = vgp[0], vreg1 = vgp[512];
    *(uint32_t*)(&Kb[0][0] + kwoff) = pk(kreg[0], kreg[1]);
    *(uint32_t*)(&Vb[0][0] + vwoff) = pk(vreg0, vreg1);
    kreg = *(const f32x2*)(kgp + 16384);
    vreg0 = vgp[16384];
    vreg1 = vgp[16384 + 512];

    // ---- Q fragments direct from global (B-operand of swapped QK) ----
    bfrag qf[2];
#pragma unroll
    for (int ks = 0; ks < 2; ++ks) {
      const float* qp = Qg + (size_t)bn * 131072 + (size_t)q * 512 + h * 64 + ks * 32 + g * 8;
      const f32x4 qa = *(const f32x4*)qp;
      const f32x4 qb = *(const f32x4*)(qp + 4);
      union { i32x4 i; bfrag b; } u;
      u.i = i32x4{(int)pk(qa.x, qa.y), (int)pk(qa.z, qa.w),
                  (int)pk(qb.x, qb.y), (int)pk(qb.z, qb.w)};
      qf[ks] = u.b;
    }

    f32x4 O[4];
#pragma unroll
    for (int ds = 0; ds < 4; ++ds) O[ds] = f32x4{0.f, 0.f, 0.f, 0.f};
    float m = -1e30f, lsum = 0.f;

    const size_t scb = (size_t)bnh << 16;
    const float* prp = Pg + scb + (size_t)q * 256 + 4 * g;   // + 16*ss + 32*st
    float* scp = Sc + scb + (size_t)q * 256 + 4 * g;

    // prior pipeline: loop-carried scalars, loaded for tile 0 here (PLAIN)
    f32x4 pr0 = *(const f32x4*)(prp);
    f32x4 pr1 = *(const f32x4*)(prp + 16);

    asm volatile("s_waitcnt lgkmcnt(0)" ::: "memory");
    __builtin_amdgcn_s_barrier();

#pragma unroll 1
    for (int st = 0; st < 8; ++st) {
      const int s0 = st * 32;
      const int p = (st & 1) << 12;
      bfrag kf[2][2];
#pragma unroll
      for (int ss = 0; ss < 2; ++ss)
#pragma unroll
        for (int ks = 0; ks < 2; ++ks)
          kf[ss][ks] = *(const bfrag*)(&Kb[0][0] + p +
              (((16 * ss + ql) * 128 + ks * 64 + g * 16) ^ swzk));

      // QK^T swapped -> D[s16][q16]; regs are s-consecutive at fixed q
      f32x4 acc[2];
#pragma unroll
      for (int ss = 0; ss < 2; ++ss) {
        f32x4 a = f32x4{0.f, 0.f, 0.f, 0.f};
        a = MFMA(kf[ss][0], qf[0], a);
        a = MFMA(kf[ss][1], qf[1], a);
        const int sb = s0 + 16 * ss + 4 * g;
        // analytic causal mask: s<=q allowed, else -1e9 (matches input mask)
#pragma unroll
        for (int r = 0; r < 4; ++r)
          a[r] = (sb + r <= q) ? a[r] : a[r] - 1e9f;
        acc[ss] = a + (ss == 0 ? pr0 : pr1);   // scores = QK + mask + prior
      }

      // prior consumed -> issue next tile's loads NOW (PLAIN)
      if (st < 7) {
        pr0 = *(const f32x4*)(prp + (st + 1) * 32);
        pr1 = *(const f32x4*)(prp + (st + 1) * 32 + 16);
      }

      // scores out -- nontemporal (R15: removing this regresses)
      __builtin_nontemporal_store(acc[0], (f32x4*)(scp + s0));
      __builtin_nontemporal_store(acc[1], (f32x4*)(scp + s0 + 16));

      if (st <= pvmax) {  // tiles fully in the causal-masked region skip softmax/PV
        float tm = fmaxf(fmaxf(fmaxf(acc[0][0], acc[0][1]), fmaxf(acc[0][2], acc[0][3])),
                         fmaxf(fmaxf(acc[1][0], acc[1][1]), fmaxf(acc[1][2], acc[1][3])));
        tm = fmaxf(tm, __shfl_xor(tm, 16));
        tm = fmaxf(tm, __shfl_xor(tm, 32));
        tm *= temp;
        const float mnew = fmaxf(m, tm);
        const float fct = __expf(m - mnew);
        m = mnew;
        float pv[8];
#pragma unroll
        for (int ss = 0; ss < 2; ++ss)
#pragma unroll
          for (int r = 0; r < 4; ++r)
            pv[ss * 4 + r] = __expf(fmaf(temp, acc[ss][r], -mnew));
        float ts = (pv[0] + pv[1]) + (pv[2] + pv[3]) + (pv[4] + pv[5]) + (pv[6] + pv[7]);
        ts += __shfl_xor(ts, 16);
        ts += __shfl_xor(ts, 32);
        lsum = lsum * fct + ts;
#pragma unroll
        for (int ds = 0; ds < 4; ++ds) O[ds] *= fct;

        // pack P to bf16 and redistribute in-register to the PV B-fragment
        // layout (lane (ql,g) needs s = s0+8g..8g+7). Held: w0 = s 4g..4g+3,
        // w1 = s 16+4g..+3. Sources: lanes g'={2g&3,(2g+1)&3}, pick by g<2.
        const int w0x = (int)pk(pv[0], pv[1]), w0y = (int)pk(pv[2], pv[3]);
        const int w1x = (int)pk(pv[4], pv[5]), w1y = (int)pk(pv[6], pv[7]);
        const int srcA = ((g & 1) << 5) + ql;       // lane of g' = (2g)&3
        const int a0 = __shfl(w0x, srcA),      a1 = __shfl(w1x, srcA);
        const int b0 = __shfl(w0y, srcA),      b1 = __shfl(w1y, srcA);
        const int c0 = __shfl(w0x, srcA + 16), c1 = __shfl(w1x, srcA + 16);
        const int d0 = __shfl(w0y, srcA + 16), d1 = __shfl(w1y, srcA + 16);
        union { i32x4 i; bfrag b; } pu;
        pu.i = i32x4{g < 2 ? a0 : a1, g < 2 ? b0 : b1,
                     g < 2 ? c0 : c1, g < 2 ? d0 : d1};

        // PV swapped: O^T[d][q] += V^T[d x s32] * P^T[s32 x q16]
        bfrag vf[4];
#pragma unroll
        for (int ds = 0; ds < 4; ++ds)
          vf[ds] = *(const bfrag*)(&Vb[0][0] + p +
              (((16 * ds + ql) * 64 + g * 16) ^ swzv));
#pragma unroll
        for (int ds = 0; ds < 4; ++ds) O[ds] = MFMA(vf[ds], pu.b, O[ds]);
      }

      // write staged K/V regs (tile st+1) into the opposite buffer, then
      // issue tile st+2 loads into the same (now free) regs
      if (st < 7) {
        const int p1 = ((st + 1) & 1) << 12;
        *(uint32_t*)(&Kb[0][0] + p1 + kwoff) = pk(kreg[0], kreg[1]);
        *(uint32_t*)(&Vb[0][0] + p1 + vwoff) = pk(vreg0, vreg1);
        if (st < 6) {
          kreg = *(const f32x2*)(kgp + (size_t)(st + 2) * 16384);
          vreg0 = vgp[(st + 2) * 16384];
          vreg1 = vgp[(st + 2) * 16384 + 512];
        }
      }
      asm volatile("s_waitcnt lgkmcnt(0)" ::: "memory");
      __builtin_amdgcn_s_barrier();
    }

    // epilogue: O /= l, store dwordx4 (d-consecutive regs)
    {
      const float inv = 1.f / lsum;
      float* op = Ov + (size_t)bn * 131072 + (size_t)q * 512 + h * 64 + 4 * g;
#pragma unroll
      for (int ds = 0; ds < 4; ++ds) {
        f32x4 o = O[ds] * inv;
        *(f32x4*)(op + 16 * ds) = o;
      }
    }
  }
}

extern "C" void kernel_launch(void* const* d_in, const int* in_sizes, int n_in,
                              void* d_out, int out_size, void* d_ws, size_t ws_size,
                              hipStream_t stream) {
  const float* Qg = (const float*)d_in[0];   // queries  [B,N,L,H,E]
  const float* Kg = (const float*)d_in[1];   // keys     [B,N,S,H,E]
  const float* Vg = (const float*)d_in[2];   // values   [B,N,S,H,D]
  const float* Pg = (const float*)d_in[4];   // attn_scores [B,N,H,L,S]
  float* Sc = (float*)d_out;                            // scores out
  float* Ov = Sc + (size_t)4 * 32 * 8 * 256 * 256;      // V out
  attn_kernel<<<dim3(256), dim3(1024), 0, stream>>>(Qg, Kg, Vg, Pg, Sc, Ov);
}

// Round 18
// 150.868 us; speedup vs baseline: 1.1606x; 1.1514x over previous
//
#include <hip/hip_runtime.h>
#include <stdint.h>

// B=4 N=32 L=S=256 H=8 E=D=64
// FINAL = R13 (best of 17 rounds, 150.2us = ~1.18x the 128us pure-stream
// floor, inside the 141-152us mixed-stream practical band):
//   - persistent 256-block grid (1 block/CU), 4 bnh per block
//   - per-tile double-buffered 4KB K/V LDS slices, XOR-swizzled
//   - raw lgkmcnt(0)+s_barrier per tile (global loads fly across barriers)
//   - swapped-operand MFMA (QK: D[s][q]; PV: D[d][q]) -> all global
//     streams are dwordx4 on s- or d-contiguous addresses
//   - depth-1 prior prefetch via loop-carried scalars (depth-2 regresses)
//   - NONTEMPORAL prior loads AND score stores (removing either: +15-25us;
//     R15/R16 falsified both directions)
//   - analytic causal mask; magic-square q-tile permutation (SIMD balance)
// Falsified levers (R3-R16): occupancy raising, barrier reduction, wider
// ILP, softmax VALU cost, desync, K-from-global, prefetch depth, cache
// policy changes. All clean variants: 150-158us.

typedef __attribute__((ext_vector_type(8))) short bfrag;   // 8 bf16 (4 VGPRs)
typedef __attribute__((ext_vector_type(4))) float f32x4;
typedef __attribute__((ext_vector_type(2))) float f32x2;
typedef __attribute__((ext_vector_type(4))) int i32x4;

__device__ __forceinline__ uint32_t f2bf(float f) {
  uint32_t u = __builtin_bit_cast(uint32_t, f);
  return (u + 0x7FFFu + ((u >> 16) & 1u)) >> 16;   // RNE f32->bf16 (finite data)
}
__device__ __forceinline__ uint32_t pk(float a, float b) {
  return f2bf(a) | (f2bf(b) << 16);
}

#define MFMA(a, b, c) __builtin_amdgcn_mfma_f32_16x16x32_bf16((a), (b), (c), 0, 0, 0)

__global__ __launch_bounds__(1024, 2) void attn_kernel(
    const float* __restrict__ Qg, const float* __restrict__ Kg,
    const float* __restrict__ Vg, const float* __restrict__ Pg,
    float* __restrict__ Sc, float* __restrict__ Ov)
{
  // K slice: [32 s][64 e] bf16, 128B rows, byte ^= (s&7)<<4   (4096 B x2)
  // V slice: [64 d][32 s] bf16, 64B rows,  byte ^= (d&3)<<4   (4096 B x2)
  __shared__ char Kb[2][4096];
  __shared__ char Vb[2][4096];

  const int t = threadIdx.x;
  const int lane = t & 63;
  const int wave = t >> 6;    // 0..15
  const int ql = lane & 15;   // q within 16-tile (MFMA col)
  const int g  = lane >> 4;   // 4-group (MFMA row group / k-slice)
  // magic-square q-tile permutation (per-SIMD PV balance)
  const int qt = (int)((0x783C96D25A1EB4F0ull >> (wave * 4)) & 15);
  const int q = qt * 16 + ql;
  const int pvmax = qt >> 1;        // causal: PV only for st <= pvmax
  const int swzk = (ql & 7) << 4;   // K slice read swizzle (lane-constant)
  const int swzv = (ql & 3) << 4;   // V slice read swizzle
  const float temp = 0.125f;        // 1/sqrt(64)

  // ---- staging roles (thread-constant) ----
  const int kr_ = t >> 5;          // K slice row 0..31
  const int kc_ = t & 31;          // K f32-pair col (floats 2*kc_)
  const int vd_ = t & 63;          // V: d
  const int vw_ = t >> 6;          // V: s-pair index 0..15
  const int kwoff = (kr_ * 128 + kc_ * 4) ^ ((kr_ & 7) << 4);
  const int vwoff = (vd_ * 64 + vw_ * 4) ^ ((vd_ & 3) << 4);

#pragma unroll 1
  for (int bi = 0; bi < 4; ++bi) {
    const int bnh = (bi << 8) + blockIdx.x;
    const int bn = bnh >> 3, h = bnh & 7;

    const float* kgp = Kg + (size_t)bn * 131072 + h * 64 + (size_t)kr_ * 512 + 2 * kc_;
    const float* vgp = Vg + (size_t)bn * 131072 + h * 64 + (size_t)(2 * vw_) * 512 + vd_;

    // ---- prologue: stage tile 0 into buf 0, then issue tile-1 loads ----
    f32x2 kreg = *(const f32x2*)kgp;
    float vreg0 = vgp[0], vreg1 = vgp[512];
    *(uint32_t*)(&Kb[0][0] + kwoff) = pk(kreg[0], kreg[1]);
    *(uint32_t*)(&Vb[0][0] + vwoff) = pk(vreg0, vreg1);
    kreg = *(const f32x2*)(kgp + 16384);
    vreg0 = vgp[16384];
    vreg1 = vgp[16384 + 512];

    // ---- Q fragments direct from global (B-operand of swapped QK) ----
    bfrag qf[2];
#pragma unroll
    for (int ks = 0; ks < 2; ++ks) {
      const float* qp = Qg + (size_t)bn * 131072 + (size_t)q * 512 + h * 64 + ks * 32 + g * 8;
      const f32x4 qa = *(const f32x4*)qp;
      const f32x4 qb = *(const f32x4*)(qp + 4);
      union { i32x4 i; bfrag b; } u;
      u.i = i32x4{(int)pk(qa.x, qa.y), (int)pk(qa.z, qa.w),
                  (int)pk(qb.x, qb.y), (int)pk(qb.z, qb.w)};
      qf[ks] = u.b;
    }

    f32x4 O[4];
#pragma unroll
    for (int ds = 0; ds < 4; ++ds) O[ds] = f32x4{0.f, 0.f, 0.f, 0.f};
    float m = -1e30f, lsum = 0.f;

    const size_t scb = (size_t)bnh << 16;
    const float* prp = Pg + scb + (size_t)q * 256 + 4 * g;   // + 16*ss + 32*st
    float* scp = Sc + scb + (size_t)q * 256 + 4 * g;

    // prior pipeline: loop-carried scalars, loaded for tile 0 here
    f32x4 pr0 = __builtin_nontemporal_load((const f32x4*)(prp));
    f32x4 pr1 = __builtin_nontemporal_load((const f32x4*)(prp + 16));

    asm volatile("s_waitcnt lgkmcnt(0)" ::: "memory");
    __builtin_amdgcn_s_barrier();

#pragma unroll 1
    for (int st = 0; st < 8; ++st) {
      const int s0 = st * 32;
      const int p = (st & 1) << 12;
      bfrag kf[2][2];
#pragma unroll
      for (int ss = 0; ss < 2; ++ss)
#pragma unroll
        for (int ks = 0; ks < 2; ++ks)
          kf[ss][ks] = *(const bfrag*)(&Kb[0][0] + p +
              (((16 * ss + ql) * 128 + ks * 64 + g * 16) ^ swzk));

      // QK^T swapped -> D[s16][q16]; regs are s-consecutive at fixed q
      f32x4 acc[2];
#pragma unroll
      for (int ss = 0; ss < 2; ++ss) {
        f32x4 a = f32x4{0.f, 0.f, 0.f, 0.f};
        a = MFMA(kf[ss][0], qf[0], a);
        a = MFMA(kf[ss][1], qf[1], a);
        const int sb = s0 + 16 * ss + 4 * g;
        // analytic causal mask: s<=q allowed, else -1e9 (matches input mask)
#pragma unroll
        for (int r = 0; r < 4; ++r)
          a[r] = (sb + r <= q) ? a[r] : a[r] - 1e9f;
        acc[ss] = a + (ss == 0 ? pr0 : pr1);   // scores = QK + mask + prior
      }

      // prior consumed -> issue next tile's loads NOW
      if (st < 7) {
        pr0 = __builtin_nontemporal_load((const f32x4*)(prp + (st + 1) * 32));
        pr1 = __builtin_nontemporal_load((const f32x4*)(prp + (st + 1) * 32 + 16));
      }

      // scores out
      __builtin_nontemporal_store(acc[0], (f32x4*)(scp + s0));
      __builtin_nontemporal_store(acc[1], (f32x4*)(scp + s0 + 16));

      if (st <= pvmax) {  // tiles fully in the causal-masked region skip softmax/PV
        float tm = fmaxf(fmaxf(fmaxf(acc[0][0], acc[0][1]), fmaxf(acc[0][2], acc[0][3])),
                         fmaxf(fmaxf(acc[1][0], acc[1][1]), fmaxf(acc[1][2], acc[1][3])));
        tm = fmaxf(tm, __shfl_xor(tm, 16));
        tm = fmaxf(tm, __shfl_xor(tm, 32));
        tm *= temp;
        const float mnew = fmaxf(m, tm);
        const float fct = __expf(m - mnew);
        m = mnew;
        float pv[8];
#pragma unroll
        for (int ss = 0; ss < 2; ++ss)
#pragma unroll
          for (int r = 0; r < 4; ++r)
            pv[ss * 4 + r] = __expf(fmaf(temp, acc[ss][r], -mnew));
        float ts = (pv[0] + pv[1]) + (pv[2] + pv[3]) + (pv[4] + pv[5]) + (pv[6] + pv[7]);
        ts += __shfl_xor(ts, 16);
        ts += __shfl_xor(ts, 32);
        lsum = lsum * fct + ts;
#pragma unroll
        for (int ds = 0; ds < 4; ++ds) O[ds] *= fct;

        // pack P to bf16 and redistribute in-register to the PV B-fragment
        // layout (lane (ql,g) needs s = s0+8g..8g+7). Held: w0 = s 4g..4g+3,
        // w1 = s 16+4g..+3. Sources: lanes g'={2g&3,(2g+1)&3}, pick by g<2.
        const int w0x = (int)pk(pv[0], pv[1]), w0y = (int)pk(pv[2], pv[3]);
        const int w1x = (int)pk(pv[4], pv[5]), w1y = (int)pk(pv[6], pv[7]);
        const int srcA = ((g & 1) << 5) + ql;       // lane of g' = (2g)&3
        const int a0 = __shfl(w0x, srcA),      a1 = __shfl(w1x, srcA);
        const int b0 = __shfl(w0y, srcA),      b1 = __shfl(w1y, srcA);
        const int c0 = __shfl(w0x, srcA + 16), c1 = __shfl(w1x, srcA + 16);
        const int d0 = __shfl(w0y, srcA + 16), d1 = __shfl(w1y, srcA + 16);
        union { i32x4 i; bfrag b; } pu;
        pu.i = i32x4{g < 2 ? a0 : a1, g < 2 ? b0 : b1,
                     g < 2 ? c0 : c1, g < 2 ? d0 : d1};

        // PV swapped: O^T[d][q] += V^T[d x s32] * P^T[s32 x q16]
        bfrag vf[4];
#pragma unroll
        for (int ds = 0; ds < 4; ++ds)
          vf[ds] = *(const bfrag*)(&Vb[0][0] + p +
              (((16 * ds + ql) * 64 + g * 16) ^ swzv));
#pragma unroll
        for (int ds = 0; ds < 4; ++ds) O[ds] = MFMA(vf[ds], pu.b, O[ds]);
      }

      // write staged K/V regs (tile st+1) into the opposite buffer, then
      // issue tile st+2 loads into the same (now free) regs
      if (st < 7) {
        const int p1 = ((st + 1) & 1) << 12;
        *(uint32_t*)(&Kb[0][0] + p1 + kwoff) = pk(kreg[0], kreg[1]);
        *(uint32_t*)(&Vb[0][0] + p1 + vwoff) = pk(vreg0, vreg1);
        if (st < 6) {
          kreg = *(const f32x2*)(kgp + (size_t)(st + 2) * 16384);
          vreg0 = vgp[(st + 2) * 16384];
          vreg1 = vgp[(st + 2) * 16384 + 512];
        }
      }
      asm volatile("s_waitcnt lgkmcnt(0)" ::: "memory");
      __builtin_amdgcn_s_barrier();
    }

    // epilogue: O /= l, store dwordx4 (d-consecutive regs)
    {
      const float inv = 1.f / lsum;
      float* op = Ov + (size_t)bn * 131072 + (size_t)q * 512 + h * 64 + 4 * g;
#pragma unroll
      for (int ds = 0; ds < 4; ++ds) {
        f32x4 o = O[ds] * inv;
        *(f32x4*)(op + 16 * ds) = o;
      }
    }
  }
}

extern "C" void kernel_launch(void* const* d_in, const int* in_sizes, int n_in,
                              void* d_out, int out_size, void* d_ws, size_t ws_size,
                              hipStream_t stream) {
  const float* Qg = (const float*)d_in[0];   // queries  [B,N,L,H,E]
  const float* Kg = (const float*)d_in[1];   // keys     [B,N,S,H,E]
  const float* Vg = (const float*)d_in[2];   // values   [B,N,S,H,D]
  const float* Pg = (const float*)d_in[4];   // attn_scores [B,N,H,L,S]
  float* Sc = (float*)d_out;                            // scores out
  float* Ov = Sc + (size_t)4 * 32 * 8 * 256 * 256;      // V out
  attn_kernel<<<dim3(256), dim3(1024), 0, stream>>>(Qg, Kg, Vg, Pg, Sc, Ov);
}